// Round 1
// baseline (185.017 us; speedup 1.0000x reference)
//
#include <hip/hip_runtime.h>
#include <hip/hip_bf16.h>
#include <string.h>

// DeformableConv2d: B=4, C=256, O=256, H=W=64, K=3, pad=1, stride=1
// Round 11: K3 n-split for occupancy (one change vs r10).
//   Grid 256->512: each block owns 32 output pixels (nh half-row) instead of
//   64. 2 blocks/CU (was 1) -> 4 waves/SIMD of independent work to hide the
//   ~200-500cy gather latency that left MfmaUtil at 8% / VALUBusy at 15% /
//   Occupancy at 21%. Lane = (pixel, ch-half): 16 channels, 32 paired
//   loads/tap (was 64); single 32x32 acc tile (16 VGPRs, was 32) frees
//   registers for deeper in-flight loads. LDS 73->40 KB.
//   Per-(channel,pixel) sampling math and per-acc K-order (kk 0..8 x ks
//   0..15) bit-identical to r10 -> absmax unchanged.
//   XCD swizzle keeps both n-halves of a row on one XCD (shared x rows in L2).
// K1, K2 byte-identical to round 10.
// Workspace: ws_off 1769472 B | ws_b 1179648 B | ws_a2 147456 B = 3096576 B.

typedef __attribute__((ext_vector_type(8))) short short8;
typedef __attribute__((ext_vector_type(8))) _Float16 half8;
typedef __attribute__((ext_vector_type(16))) float floatx16;

__device__ __forceinline__ unsigned bfbits(float f) {
    unsigned u;
    __builtin_memcpy(&u, &f, 4);
    return (u + 0x7fffu + ((u >> 16) & 1u)) >> 16;   // RNE f32->bf16
}
__device__ __forceinline__ unsigned pack_bf16(float lo, float hi) {
    return bfbits(lo) | (bfbits(hi) << 16);
}
__device__ __forceinline__ unsigned pack_f16(float lo, float hi) {
    _Float16 a = (_Float16)lo, b = (_Float16)hi;
    unsigned short ua, ub;
    __builtin_memcpy(&ua, &a, 2);
    __builtin_memcpy(&ub, &b, 2);
    return (unsigned)ua | ((unsigned)ub << 16);
}

// async global->LDS DMA, 4 B per lane; lane l's data lands at lds + l*4
__device__ __forceinline__ void gl_lds4(const float* g, float* l) {
    __builtin_amdgcn_global_load_lds(
        (const __attribute__((address_space(1))) unsigned int*)g,
        (__attribute__((address_space(3))) unsigned int*)l,
        4, 0, 0);
}

// ---------------------------------------------------------------------------
// K1: weight pack (verbatim rounds 4-10).
// ---------------------------------------------------------------------------
__global__ __launch_bounds__(256) void weight_pack_kernel(
    const float* __restrict__ w, const float* __restrict__ off_w,
    const float* __restrict__ mask_w,
    unsigned short* __restrict__ ws_b, unsigned short* __restrict__ ws_a2)
{
    __shared__ float slab[32 * 289];
    const int bid = blockIdx.x;
    const int tid = threadIdx.x;

    if (bid < 64) {
        const int nt = bid >> 3, cb = bid & 7;
        const float* wbase = w + (size_t)nt * 32 * 2304 + cb * 288;
#pragma unroll
        for (int i = 0; i < 9; ++i) {
            int idx = i * 256 + tid;               // 0..2303
            int o = idx / 72, f4 = idx % 72;
            float4 v = *(const float4*)&wbase[(size_t)o * 2304 + f4 * 4];
            slab[o * 289 + f4 * 4 + 0] = v.x;
            slab[o * 289 + f4 * 4 + 1] = v.y;
            slab[o * 289 + f4 * 4 + 2] = v.z;
            slab[o * 289 + f4 * 4 + 3] = v.w;
        }
        __syncthreads();
#pragma unroll
        for (int pass = 0; pass < 5; ++pass) {
            int rid = pass * 8 + (tid >> 5);
            if (rid < 36) {
                int kk = rid >> 2, q = rid & 3;
                int no = tid & 31;
                unsigned pk[4];
#pragma unroll
                for (int i = 0; i < 4; ++i) {
                    float f0 = slab[no * 289 + (q * 8 + 2 * i) * 9 + kk];
                    float f1 = slab[no * 289 + (q * 8 + 2 * i + 1) * 9 + kk];
                    pk[i] = pack_bf16(f0, f1);
                }
                size_t u = ((size_t)nt * 288 + kk * 32 + cb * 4 + q) * 32 + no;
                *(uint4*)&ws_b[u * 8] = make_uint4(pk[0], pk[1], pk[2], pk[3]);
            }
        }
    } else {
        int e = (bid - 64) * 256 + tid;       // 0..9215
        int lan = e & 31;                     // oc row
        int ku = e >> 5;                      // 0..287
        int kk = ku >> 5;
        int c0 = (ku & 31) * 8;
        int o = lan;
        float f[8];
#pragma unroll
        for (int j = 0; j < 8; ++j) {
            int c = c0 + j;
            float v = 0.f;
            if (o < 18)      v = off_w[((size_t)o * 256 + c) * 9 + kk];
            else if (o < 27) v = mask_w[((size_t)(o - 18) * 256 + c) * 9 + kk];
            f[j] = v;
        }
        unsigned pk[4];
#pragma unroll
        for (int i = 0; i < 4; ++i) pk[i] = pack_f16(f[2 * i], f[2 * i + 1]);
        *(uint4*)&ws_a2[(size_t)e * 8] = make_uint4(pk[0], pk[1], pk[2], pk[3]);
    }
}

// ---------------------------------------------------------------------------
// K2: offset/mask conv via f16 MFMA with global_load_lds staging
// (verbatim rounds 9-10).
// ---------------------------------------------------------------------------
__global__ __launch_bounds__(512) void offmask_mfma_kernel(
    const float* __restrict__ x, const unsigned short* __restrict__ ws_a2,
    const float* __restrict__ off_b, const float* __restrict__ mask_b,
    float* __restrict__ ws_off)
{
    __shared__ float stage[256 * 64];     // 64 KiB: x[.][hh][.] for one row
    __shared__ uint4 bufB[2][2048];       // 64 KiB; aliased as red[] in epilogue
    const int bid = blockIdx.x;
    const int row = (bid & 7) * 32 + (bid >> 3);
    const int b = row >> 6, ho = row & 63;
    const int tid = threadIdx.x;
    const int l = tid & 63;
    const int w = tid >> 6;
    const int lan = l & 31, h = l >> 5;
    const float* xb = x + (size_t)b * 256 * 4096;

    floatx16 acc;
#pragma unroll
    for (int r = 0; r < 16; ++r) acc[r] = 0.f;

    const int n = l;                 // pixel within row
    const int ku0 = w;               // 0..7
    const int ntile = w >> 2, kq = w & 3;

    auto stage_row = [&](int hh) {
        if (hh >= 0 && hh < 64) {
            const float* src = xb + hh * 64;
#pragma unroll
            for (int i = 0; i < 32; ++i) {
                int c = w * 32 + i;                 // wave-uniform channel
                gl_lds4(src + (size_t)c * 4096 + l, &stage[c * 64]);
            }
        } else {
#pragma unroll
            for (int i = 0; i < 32; ++i) {
                int c = w * 32 + i;
                stage[c * 64 + l] = 0.f;
            }
        }
    };

    auto build = [&](int kk, int kx) {
        int px = n - 1 + kx;
        bool vx = (px >= 0 && px < 64);
        int pxc = vx ? px : 0;
        int buf = kk & 1;
#pragma unroll
        for (int j = 0; j < 4; ++j) {
            int ku = ku0 + 8 * j;
            int c0 = ku * 8;
            float v[8];
#pragma unroll
            for (int jj = 0; jj < 8; ++jj) {
                float t = stage[(c0 + jj) * 64 + pxc];
                v[jj] = vx ? t : 0.f;
            }
            unsigned pk[4];
#pragma unroll
            for (int i = 0; i < 4; ++i) pk[i] = pack_f16(v[2 * i], v[2 * i + 1]);
            bufB[buf][ku * 64 + n] = make_uint4(pk[0], pk[1], pk[2], pk[3]);
        }
    };

    auto domfma = [&](int kk) {
        int buf = kk & 1;
        const uint4* a4 = (const uint4*)ws_a2;
#pragma unroll
        for (int s4 = 0; s4 < 4; ++s4) {
            int s = kq * 4 + s4;         // K-step 0..15 within chunk
            int kul = s * 2 + h;         // local ku 0..31
            uint4 ua = a4[(size_t)(kk * 32 + kul) * 32 + lan];
            uint4 ub = bufB[buf][kul * 64 + ntile * 32 + lan];
            half8 a, bb;
            __builtin_memcpy(&a, &ua, 16);
            __builtin_memcpy(&bb, &ub, 16);
            acc = __builtin_amdgcn_mfma_f32_32x32x16_f16(a, bb, acc, 0, 0, 0);
        }
    };

    for (int ky = 0; ky < 3; ++ky) {
        __syncthreads();                 // prior builds done reading stage
        stage_row(ho - 1 + ky);
        __syncthreads();                 // DMA drained (vmcnt(0) before barrier)
#pragma unroll
        for (int kx = 0; kx < 3; ++kx) {
            int kk = ky * 3 + kx;
            build(kk, kx);
            __syncthreads();
            domfma(kk);
        }
    }
    __syncthreads();                     // last domfma done before red alias

    // cross-wave partial-C reduction (4 K-quarters per n-tile) - verbatim
    float* red = (float*)bufB;           // 8 waves x 64 lanes x 16 = 32 KiB
#pragma unroll
    for (int r = 0; r < 16; ++r) red[(w * 64 + l) * 16 + r] = acc[r];
    __syncthreads();
    for (int idx = tid; idx < 27 * 64; idx += 512) {
        int oc = idx >> 6, wo = idx & 63;
        int nt2 = wo >> 5, nn = wo & 31;
        int h2 = (oc >> 2) & 1;
        int r = (oc & 3) | ((oc >> 3) << 2);
        int lane2 = nn + 32 * h2;
        float s = 0.f;
#pragma unroll
        for (int kq2 = 0; kq2 < 4; ++kq2)
            s += red[((nt2 * 4 + kq2) * 64 + lane2) * 16 + r];
        float v;
        if (oc < 18) {
            v = s + off_b[oc];
        } else {
            float t = s + mask_b[oc - 18];
            v = 1.f / (1.f + expf(-t));
        }
        ws_off[(size_t)row * 1728 + idx] = v;
    }
}

// ---------------------------------------------------------------------------
// K3: fused deformable sampling + GEMM, n-split.  512 blocks, 512 threads /
// 8 waves.  Block = (row, n-half): 32 output pixels.  Wave wid samples its
// 32-channel unit (lane = (pixel, ch-half), 16 ch per lane) and owns m-tile
// wid (o = wid*32..wid*32+31, one 32-px n-tile).  One barrier per tap.
// Sampling math and MFMA K-order identical to r10 (bit-identical outputs).
// ---------------------------------------------------------------------------
__global__ __launch_bounds__(512) void deform_gemm_kernel(
    const float* __restrict__ x, const float* __restrict__ ws_off,
    const unsigned short* __restrict__ ws_b, const float* __restrict__ bias,
    float* __restrict__ out)
{
    __shared__ float offs[1728];
    __shared__ float biasl[256];
    __shared__ uint4 tile[2][1024];   // [buf][ku(32)*32 + n] : 8 bf16 each, 2x16KB

    const int bid = blockIdx.x;
    // both n-halves of a row land on the same XCD (bid%8), adjacent slots
    const int row = (bid & 7) * 32 + (bid >> 4);
    const int n0 = ((bid >> 3) & 1) * 32;      // n-half base pixel
    const int b = row >> 6, ho = row & 63;
    const int tid = threadIdx.x;
    const int l = tid & 63;
    const int wid = tid >> 6;          // 0..7
    const int lan = l & 31;            // pixel within half / MFMA lane
    const int h = l >> 5;              // channel sub-half / MFMA K-half

    for (int i = tid; i < 1728; i += 512) offs[i] = ws_off[(size_t)row * 1728 + i];
    if (tid < 256) biasl[tid] = bias[tid];
    __syncthreads();

    const float* xb = x + (size_t)b * 256 * 4096;
    const uint4* wb4 = (const uint4*)ws_b;

    // producer per-tap state: premultiplied weight pairs + row base offsets
    float a00 = 0.f, a01 = 0.f, a10 = 0.f, a11 = 0.f;
    int e0 = 0, e1 = 0;

    // consumer accumulator: m-tile wid x 1 n-tile
    floatx16 acc;
#pragma unroll
    for (int r = 0; r < 16; ++r) acc[r] = 0.f;

    auto compute_tap = [&](int kk) {
        int ky = kk / 3, kx = kk - ky * 3;
        int pxg = n0 + lan;                    // global output pixel
        float dy = offs[(2 * kk) * 64 + pxg];
        float dx = offs[(2 * kk + 1) * 64 + pxg];
        float mk = offs[(18 + kk) * 64 + pxg];
        float py = (float)(ho - 1 + ky) + dy;
        float px = (float)(pxg - 1 + kx) + dx;
        float y0f = floorf(py), x0f = floorf(px);
        float wy1 = py - y0f, wx1 = px - x0f;
        float wy0 = 1.f - wy1, wx0 = 1.f - wx1;
        int y0 = (int)y0f, xi0 = (int)x0f;
        int y1 = y0 + 1;
        float vy0 = (y0 >= 0 && y0 < 64) ? 1.f : 0.f;
        float vy1 = (y1 >= 0 && y1 < 64) ? 1.f : 0.f;
        float vx0 = (xi0 >= 0 && xi0 < 64) ? 1.f : 0.f;
        float vx1 = (xi0 >= -1 && xi0 < 63) ? 1.f : 0.f;   // validity of xi0+1
        float wxa, wxb;
        if (xi0 < 0)        { wxa = wx1 * vx1; wxb = 0.f; }        // corner1 lands at v.x
        else if (xi0 >= 63) { wxa = 0.f;       wxb = wx0 * vx0; }  // corner0 lands at v.y
        else                { wxa = wx0;       wxb = wx1; }        // both valid
        float wr0 = wy0 * vy0 * mk, wr1 = wy1 * vy1 * mk;
        a00 = wr0 * wxa; a01 = wr0 * wxb;
        a10 = wr1 * wxa; a11 = wr1 * wxb;
        int yc0 = min(max(y0, 0), 63), yc1 = min(max(y1, 0), 63);
        int bx = min(max(xi0, 0), 62);
        e0 = yc0 * 64 + bx;
        e1 = yc1 * 64 + bx;
    };

    auto sample_unit = [&](int buf) {
        const int kub = wid * 4 + h * 2;            // 2 ku groups for this lane
        const float* bp = xb + (size_t)(kub * 8) * 4096;
#pragma unroll
        for (int u = 0; u < 2; ++u) {
            unsigned pk[4];
#pragma unroll
            for (int j = 0; j < 4; ++j) {
                const float* q0 = bp + (size_t)(u * 8 + 2 * j) * 4096;
                const float* q1 = q0 + 4096;
                float2 r0a, r0b, r1a, r1b;
                __builtin_memcpy(&r0a, q0 + e0, 8);
                __builtin_memcpy(&r0b, q0 + e1, 8);
                __builtin_memcpy(&r1a, q1 + e0, 8);
                __builtin_memcpy(&r1b, q1 + e1, 8);
                float v0 = a00 * r0a.x + a01 * r0a.y + a10 * r0b.x + a11 * r0b.y;
                float v1 = a00 * r1a.x + a01 * r1a.y + a10 * r1b.x + a11 * r1b.y;
                pk[j] = pack_bf16(v0, v1);
            }
            tile[buf][(kub + u) * 32 + lan] = make_uint4(pk[0], pk[1], pk[2], pk[3]);
        }
    };

    auto do_mfma = [&](int kk, int buf) {
#pragma unroll
        for (int ks = 0; ks < 16; ++ks) {
            int kul = ks * 2 + h;          // local ku 0..31
            uint4 ua = wb4[((size_t)wid * 288 + kk * 32 + kul) * 32 + lan];
            uint4 ub = tile[buf][kul * 32 + lan];
            short8 a, bb;
            __builtin_memcpy(&a, &ua, 16);
            __builtin_memcpy(&bb, &ub, 16);
            acc = __builtin_amdgcn_mfma_f32_32x32x16_bf16(a, bb, acc, 0, 0, 0);
        }
    };

    compute_tap(0);
    sample_unit(0);
    __syncthreads();

    for (int kk = 0; kk < 9; ++kk) {
        if (kk + 1 < 9) {
            compute_tap(kk + 1);
            sample_unit((kk + 1) & 1);
        }
        do_mfma(kk, kk & 1);
        __syncthreads();
    }

    // epilogue: wave wid owns m-tile wid, pixels n0..n0+31
#pragma unroll
    for (int r = 0; r < 16; ++r) {
        int o = wid * 32 + (r & 3) + 8 * (r >> 2) + 4 * h;
        out[(((size_t)b * 256 + o) * 64 + ho) * 64 + n0 + lan] = acc[r] + biasl[o];
    }
}

extern "C" void kernel_launch(void* const* d_in, const int* in_sizes, int n_in,
                              void* d_out, int out_size, void* d_ws, size_t ws_size,
                              hipStream_t stream) {
    const float* x      = (const float*)d_in[0];
    const float* weight = (const float*)d_in[1];
    const float* bias   = (const float*)d_in[2];
    const float* off_w  = (const float*)d_in[3];
    const float* off_b  = (const float*)d_in[4];
    const float* mask_w = (const float*)d_in[5];
    const float* mask_b = (const float*)d_in[6];
    float* out = (float*)d_out;

    float* ws_off = (float*)d_ws;                                      // 1,769,472 B
    unsigned short* ws_b  = (unsigned short*)((char*)d_ws + 1769472);  // 1,179,648 B
    unsigned short* ws_a2 = (unsigned short*)((char*)d_ws + 2949120);  //   147,456 B

    hipLaunchKernelGGL(weight_pack_kernel, dim3(100), dim3(256), 0, stream,
                       weight, off_w, mask_w, ws_b, ws_a2);
    hipLaunchKernelGGL(offmask_mfma_kernel, dim3(256), dim3(512), 0, stream,
                       x, ws_a2, off_b, mask_b, ws_off);
    hipLaunchKernelGGL(deform_gemm_kernel, dim3(512), dim3(512), 0, stream,
                       x, ws_off, ws_b, bias, out);
}

// Round 2
// 160.157 us; speedup vs baseline: 1.1552x; 1.1552x over previous
//
#include <hip/hip_runtime.h>
#include <hip/hip_bf16.h>
#include <string.h>

// DeformableConv2d: B=4, C=256, O=256, H=W=64, K=3, pad=1, stride=1
// Round 12: K3 gather restructure (the one change) + helper K0.
//   r11 post-mortem: doubling blocks/CU changed nothing -> K3 is bound by
//   divergent-address throughput (~1.3 lane-addr/cyc/CU on 75.5M scattered
//   8B requests), not latency. Fix: transpose x to (B,H,W,C) fp16 (K0) so a
//   bilinear corner = 256 contiguous channels = ONE coalesced wave-load
//   (lanes=channels). Per (pixel,tap): 4 wave-uniform 512B loads, f32
//   combine, swizzled ds_write_b128 into the same MFMA tile layout.
//   75.5M divergent -> 2.1M coalesced requests; gather bytes 604->302 MB
//   (fp16), L2-resident. Corner weights/coords/FMA order/bf16 pack/K-order
//   preserved; only new rounding is fp16 quantization of x (~2^-11).
// K1, K2 byte-identical to rounds 9-11.
// Workspace: ws_off 1769472 | ws_b 1179648 | ws_a2 147456 | xt 8388608
//          = 11,485,184 B.

typedef __attribute__((ext_vector_type(8))) short short8;
typedef __attribute__((ext_vector_type(8))) _Float16 half8;
typedef __attribute__((ext_vector_type(16))) float floatx16;

__device__ __forceinline__ unsigned bfbits(float f) {
    unsigned u;
    __builtin_memcpy(&u, &f, 4);
    return (u + 0x7fffu + ((u >> 16) & 1u)) >> 16;   // RNE f32->bf16
}
__device__ __forceinline__ unsigned pack_bf16(float lo, float hi) {
    return bfbits(lo) | (bfbits(hi) << 16);
}
__device__ __forceinline__ unsigned pack_f16(float lo, float hi) {
    _Float16 a = (_Float16)lo, b = (_Float16)hi;
    unsigned short ua, ub;
    __builtin_memcpy(&ua, &a, 2);
    __builtin_memcpy(&ub, &b, 2);
    return (unsigned)ua | ((unsigned)ub << 16);
}

// async global->LDS DMA, 4 B per lane; lane l's data lands at lds + l*4
__device__ __forceinline__ void gl_lds4(const float* g, float* l) {
    __builtin_amdgcn_global_load_lds(
        (const __attribute__((address_space(1))) unsigned int*)g,
        (__attribute__((address_space(3))) unsigned int*)l,
        4, 0, 0);
}

// ---------------------------------------------------------------------------
// K0: x (B,C,H,W) f32 -> xt (B,H,W,C) f16.  One block per (b, y) row.
// ---------------------------------------------------------------------------
__global__ __launch_bounds__(256) void xpose_hwc_kernel(
    const float* __restrict__ x, unsigned short* __restrict__ xt)
{
    __shared__ float stage[256 * 65];
    const int bid = blockIdx.x;          // (b*64 + y)
    const int b = bid >> 6, y = bid & 63;
    const int tid = threadIdx.x;
    const float* src = x + (size_t)b * 256 * 4096 + y * 64;

#pragma unroll
    for (int i = 0; i < 16; ++i) {
        int idx = i * 256 + tid;         // 0..4095 = (c, xq)
        int c = idx >> 4, xq = idx & 15;
        float4 v = *(const float4*)&src[(size_t)c * 4096 + xq * 4];
        stage[c * 65 + xq * 4 + 0] = v.x;
        stage[c * 65 + xq * 4 + 1] = v.y;
        stage[c * 65 + xq * 4 + 2] = v.z;
        stage[c * 65 + xq * 4 + 3] = v.w;
    }
    __syncthreads();

    unsigned short* dst = xt + (size_t)bid * 16384;   // 64 px * 256 ch
#pragma unroll
    for (int i = 0; i < 32; ++i) {
        int c2 = (tid & 127) * 2;
        int xx = i * 2 + (tid >> 7);
        float f0 = stage[c2 * 65 + xx];
        float f1 = stage[(c2 + 1) * 65 + xx];
        *(unsigned*)&dst[xx * 256 + c2] = pack_f16(f0, f1);
    }
}

// ---------------------------------------------------------------------------
// K1: weight pack (verbatim rounds 4-11).
// ---------------------------------------------------------------------------
__global__ __launch_bounds__(256) void weight_pack_kernel(
    const float* __restrict__ w, const float* __restrict__ off_w,
    const float* __restrict__ mask_w,
    unsigned short* __restrict__ ws_b, unsigned short* __restrict__ ws_a2)
{
    __shared__ float slab[32 * 289];
    const int bid = blockIdx.x;
    const int tid = threadIdx.x;

    if (bid < 64) {
        const int nt = bid >> 3, cb = bid & 7;
        const float* wbase = w + (size_t)nt * 32 * 2304 + cb * 288;
#pragma unroll
        for (int i = 0; i < 9; ++i) {
            int idx = i * 256 + tid;               // 0..2303
            int o = idx / 72, f4 = idx % 72;
            float4 v = *(const float4*)&wbase[(size_t)o * 2304 + f4 * 4];
            slab[o * 289 + f4 * 4 + 0] = v.x;
            slab[o * 289 + f4 * 4 + 1] = v.y;
            slab[o * 289 + f4 * 4 + 2] = v.z;
            slab[o * 289 + f4 * 4 + 3] = v.w;
        }
        __syncthreads();
#pragma unroll
        for (int pass = 0; pass < 5; ++pass) {
            int rid = pass * 8 + (tid >> 5);
            if (rid < 36) {
                int kk = rid >> 2, q = rid & 3;
                int no = tid & 31;
                unsigned pk[4];
#pragma unroll
                for (int i = 0; i < 4; ++i) {
                    float f0 = slab[no * 289 + (q * 8 + 2 * i) * 9 + kk];
                    float f1 = slab[no * 289 + (q * 8 + 2 * i + 1) * 9 + kk];
                    pk[i] = pack_bf16(f0, f1);
                }
                size_t u = ((size_t)nt * 288 + kk * 32 + cb * 4 + q) * 32 + no;
                *(uint4*)&ws_b[u * 8] = make_uint4(pk[0], pk[1], pk[2], pk[3]);
            }
        }
    } else {
        int e = (bid - 64) * 256 + tid;       // 0..9215
        int lan = e & 31;                     // oc row
        int ku = e >> 5;                      // 0..287
        int kk = ku >> 5;
        int c0 = (ku & 31) * 8;
        int o = lan;
        float f[8];
#pragma unroll
        for (int j = 0; j < 8; ++j) {
            int c = c0 + j;
            float v = 0.f;
            if (o < 18)      v = off_w[((size_t)o * 256 + c) * 9 + kk];
            else if (o < 27) v = mask_w[((size_t)(o - 18) * 256 + c) * 9 + kk];
            f[j] = v;
        }
        unsigned pk[4];
#pragma unroll
        for (int i = 0; i < 4; ++i) pk[i] = pack_f16(f[2 * i], f[2 * i + 1]);
        *(uint4*)&ws_a2[(size_t)e * 8] = make_uint4(pk[0], pk[1], pk[2], pk[3]);
    }
}

// ---------------------------------------------------------------------------
// K2: offset/mask conv via f16 MFMA with global_load_lds staging
// (verbatim rounds 9-11).
// ---------------------------------------------------------------------------
__global__ __launch_bounds__(512) void offmask_mfma_kernel(
    const float* __restrict__ x, const unsigned short* __restrict__ ws_a2,
    const float* __restrict__ off_b, const float* __restrict__ mask_b,
    float* __restrict__ ws_off)
{
    __shared__ float stage[256 * 64];     // 64 KiB: x[.][hh][.] for one row
    __shared__ uint4 bufB[2][2048];       // 64 KiB; aliased as red[] in epilogue
    const int bid = blockIdx.x;
    const int row = (bid & 7) * 32 + (bid >> 3);
    const int b = row >> 6, ho = row & 63;
    const int tid = threadIdx.x;
    const int l = tid & 63;
    const int w = tid >> 6;
    const int lan = l & 31, h = l >> 5;
    const float* xb = x + (size_t)b * 256 * 4096;

    floatx16 acc;
#pragma unroll
    for (int r = 0; r < 16; ++r) acc[r] = 0.f;

    const int n = l;                 // pixel within row
    const int ku0 = w;               // 0..7
    const int ntile = w >> 2, kq = w & 3;

    auto stage_row = [&](int hh) {
        if (hh >= 0 && hh < 64) {
            const float* src = xb + hh * 64;
#pragma unroll
            for (int i = 0; i < 32; ++i) {
                int c = w * 32 + i;                 // wave-uniform channel
                gl_lds4(src + (size_t)c * 4096 + l, &stage[c * 64]);
            }
        } else {
#pragma unroll
            for (int i = 0; i < 32; ++i) {
                int c = w * 32 + i;
                stage[c * 64 + l] = 0.f;
            }
        }
    };

    auto build = [&](int kk, int kx) {
        int px = n - 1 + kx;
        bool vx = (px >= 0 && px < 64);
        int pxc = vx ? px : 0;
        int buf = kk & 1;
#pragma unroll
        for (int j = 0; j < 4; ++j) {
            int ku = ku0 + 8 * j;
            int c0 = ku * 8;
            float v[8];
#pragma unroll
            for (int jj = 0; jj < 8; ++jj) {
                float t = stage[(c0 + jj) * 64 + pxc];
                v[jj] = vx ? t : 0.f;
            }
            unsigned pk[4];
#pragma unroll
            for (int i = 0; i < 4; ++i) pk[i] = pack_f16(v[2 * i], v[2 * i + 1]);
            bufB[buf][ku * 64 + n] = make_uint4(pk[0], pk[1], pk[2], pk[3]);
        }
    };

    auto domfma = [&](int kk) {
        int buf = kk & 1;
        const uint4* a4 = (const uint4*)ws_a2;
#pragma unroll
        for (int s4 = 0; s4 < 4; ++s4) {
            int s = kq * 4 + s4;         // K-step 0..15 within chunk
            int kul = s * 2 + h;         // local ku 0..31
            uint4 ua = a4[(size_t)(kk * 32 + kul) * 32 + lan];
            uint4 ub = bufB[buf][kul * 64 + ntile * 32 + lan];
            half8 a, bb;
            __builtin_memcpy(&a, &ua, 16);
            __builtin_memcpy(&bb, &ub, 16);
            acc = __builtin_amdgcn_mfma_f32_32x32x16_f16(a, bb, acc, 0, 0, 0);
        }
    };

    for (int ky = 0; ky < 3; ++ky) {
        __syncthreads();                 // prior builds done reading stage
        stage_row(ho - 1 + ky);
        __syncthreads();                 // DMA drained (vmcnt(0) before barrier)
#pragma unroll
        for (int kx = 0; kx < 3; ++kx) {
            int kk = ky * 3 + kx;
            build(kk, kx);
            __syncthreads();
            domfma(kk);
        }
    }
    __syncthreads();                     // last domfma done before red alias

    // cross-wave partial-C reduction (4 K-quarters per n-tile) - verbatim
    float* red = (float*)bufB;           // 8 waves x 64 lanes x 16 = 32 KiB
#pragma unroll
    for (int r = 0; r < 16; ++r) red[(w * 64 + l) * 16 + r] = acc[r];
    __syncthreads();
    for (int idx = tid; idx < 27 * 64; idx += 512) {
        int oc = idx >> 6, wo = idx & 63;
        int nt2 = wo >> 5, nn = wo & 31;
        int h2 = (oc >> 2) & 1;
        int r = (oc & 3) | ((oc >> 3) << 2);
        int lane2 = nn + 32 * h2;
        float s = 0.f;
#pragma unroll
        for (int kq2 = 0; kq2 < 4; ++kq2)
            s += red[((nt2 * 4 + kq2) * 64 + lane2) * 16 + r];
        float v;
        if (oc < 18) {
            v = s + off_b[oc];
        } else {
            float t = s + mask_b[oc - 18];
            v = 1.f / (1.f + expf(-t));
        }
        ws_off[(size_t)row * 1728 + idx] = v;
    }
}

// ---------------------------------------------------------------------------
// K3: fused deformable sampling + GEMM, coalesced-gather edition.
// 256 blocks, 512 threads / 8 waves, 64 px/block (r10 geometry).
// Producer: per tap, wave wid builds pixels wid*8..wid*8+7; per iter the
// wave does 2 pixels (lane halves), lanes = channel-groups: 4 wave-uniform
// 512B corner loads from xt (f16 HWC), f32 weighted combine, one swizzled
// ds_write_b128 into tile[ku][n].  Consumer: identical MFMA/K-order to r10.
// ---------------------------------------------------------------------------
__global__ __launch_bounds__(512) void deform_gemm_kernel(
    const unsigned short* __restrict__ xt, const float* __restrict__ ws_off,
    const unsigned short* __restrict__ ws_b, const float* __restrict__ bias,
    float* __restrict__ out)
{
    __shared__ float params[576 * 8];   // per (tap,px): 4 weights + 4 byte-offsets
    __shared__ float biasl[256];
    __shared__ uint4 tile[2][2048];     // [buf][ku(32)*64 + n], XOR-swizzled

    const int bid = blockIdx.x;
    const int row = (bid & 7) * 32 + (bid >> 3);
    const int b = row >> 6, ho = row & 63;
    const int tid = threadIdx.x;
    const int l = tid & 63;
    const int wid = tid >> 6;          // 0..7
    const int lan = l & 31;            // channel-group (producer) / MFMA lane
    const int h = l >> 5;              // pixel-parity (producer) / MFMA K-half

    if (tid < 256) biasl[tid] = bias[tid];

    // ---- per-(tap,pixel) sampling params: weights + clamped corner offsets
    {
        const float* ob = ws_off + (size_t)row * 1728;
        for (int it = tid; it < 576; it += 512) {
            int kk = it >> 6, p = it & 63;
            float dy = ob[(2 * kk) * 64 + p];
            float dx = ob[(2 * kk + 1) * 64 + p];
            float mk = ob[(18 + kk) * 64 + p];
            int ky = kk / 3, kx = kk - ky * 3;
            float py = (float)(ho - 1 + ky) + dy;
            float px = (float)(p - 1 + kx) + dx;
            float y0f = floorf(py), x0f = floorf(px);
            float wy1 = py - y0f, wx1 = px - x0f;
            float wy0 = 1.f - wy1, wx0 = 1.f - wx1;
            int y0 = (int)y0f, xi0 = (int)x0f;
            int y1 = y0 + 1, xi1 = xi0 + 1;
            float vy0 = (y0 >= 0 && y0 < 64) ? 1.f : 0.f;
            float vy1 = (y1 >= 0 && y1 < 64) ? 1.f : 0.f;
            float vx0 = (xi0 >= 0 && xi0 < 64) ? 1.f : 0.f;
            float vx1 = (xi1 >= 0 && xi1 < 64) ? 1.f : 0.f;
            float wr0 = wy0 * vy0 * mk, wr1 = wy1 * vy1 * mk;
            float wa = wx0 * vx0, wb2 = wx1 * vx1;
            int yc0 = min(max(y0, 0), 63), yc1 = min(max(y1, 0), 63);
            int xc0 = min(max(xi0, 0), 63), xc1 = min(max(xi1, 0), 63);
            float* pr = &params[it * 8];
            pr[0] = wr0 * wa;  pr[1] = wr0 * wb2;
            pr[2] = wr1 * wa;  pr[3] = wr1 * wb2;
            pr[4] = __int_as_float((yc0 * 64 + xc0) << 9);   // *512 B
            pr[5] = __int_as_float((yc0 * 64 + xc1) << 9);
            pr[6] = __int_as_float((yc1 * 64 + xc0) << 9);
            pr[7] = __int_as_float((yc1 * 64 + xc1) << 9);
        }
    }
    __syncthreads();

    const char* xb16 = (const char*)xt + ((size_t)b << 21);   // b * 2 MiB
    const uint4* wb4 = (const uint4*)ws_b;

    floatx16 acc0, acc1;
#pragma unroll
    for (int r = 0; r < 16; ++r) { acc0[r] = 0.f; acc1[r] = 0.f; }

    auto produce = [&](int kk, int buf) {
        char* tb = (char*)&tile[buf][0];
#pragma unroll
        for (int i = 0; i < 4; ++i) {
            int p = wid * 8 + 2 * i + h;
            const float* pr = &params[(kk * 64 + p) * 8];
            float4 wv; int4 ov;
            __builtin_memcpy(&wv, pr, 16);
            __builtin_memcpy(&ov, pr + 4, 16);
            uint4 q00, q01, q10, q11;
            __builtin_memcpy(&q00, xb16 + ov.x + (lan << 4), 16);
            __builtin_memcpy(&q01, xb16 + ov.y + (lan << 4), 16);
            __builtin_memcpy(&q10, xb16 + ov.z + (lan << 4), 16);
            __builtin_memcpy(&q11, xb16 + ov.w + (lan << 4), 16);
            half8 h00, h01, h10, h11;
            __builtin_memcpy(&h00, &q00, 16);
            __builtin_memcpy(&h01, &q01, 16);
            __builtin_memcpy(&h10, &q10, 16);
            __builtin_memcpy(&h11, &q11, 16);
            unsigned pk[4];
#pragma unroll
            for (int j = 0; j < 4; ++j) {
                float v0 = wv.x * (float)h00[2 * j]     + wv.y * (float)h01[2 * j]
                         + wv.z * (float)h10[2 * j]     + wv.w * (float)h11[2 * j];
                float v1 = wv.x * (float)h00[2 * j + 1] + wv.y * (float)h01[2 * j + 1]
                         + wv.z * (float)h10[2 * j + 1] + wv.w * (float)h11[2 * j + 1];
                pk[j] = pack_bf16(v0, v1);
            }
            uint4 wv4 = make_uint4(pk[0], pk[1], pk[2], pk[3]);
            __builtin_memcpy(tb + lan * 1024 + ((p << 4) ^ (lan << 4)), &wv4, 16);
        }
    };

    auto do_mfma = [&](int kk, int buf) {
        const char* tb = (const char*)&tile[buf][0];
#pragma unroll
        for (int ks = 0; ks < 16; ++ks) {
            int kul = ks * 2 + h;          // local ku 0..31
            uint4 ua = wb4[((size_t)wid * 288 + kk * 32 + kul) * 32 + lan];
            uint4 ub0, ub1;
            __builtin_memcpy(&ub0, tb + kul * 1024 + (((lan) << 4) ^ (kul << 4)), 16);
            __builtin_memcpy(&ub1, tb + kul * 1024 + (((32 + lan) << 4) ^ (kul << 4)), 16);
            short8 a, b0, b1;
            __builtin_memcpy(&a, &ua, 16);
            __builtin_memcpy(&b0, &ub0, 16);
            __builtin_memcpy(&b1, &ub1, 16);
            acc0 = __builtin_amdgcn_mfma_f32_32x32x16_bf16(a, b0, acc0, 0, 0, 0);
            acc1 = __builtin_amdgcn_mfma_f32_32x32x16_bf16(a, b1, acc1, 0, 0, 0);
        }
    };

    produce(0, 0);
    __syncthreads();

    for (int kk = 0; kk < 9; ++kk) {
        if (kk + 1 < 9) produce(kk + 1, (kk + 1) & 1);
        do_mfma(kk, kk & 1);
        __syncthreads();
    }

    // epilogue: wave wid owns m-tile wid, 2 n-tiles (r10 verbatim)
#pragma unroll
    for (int nt = 0; nt < 2; ++nt) {
#pragma unroll
        for (int r = 0; r < 16; ++r) {
            int o = wid * 32 + (r & 3) + 8 * (r >> 2) + 4 * h;
            int woo = nt * 32 + lan;
            float v = (nt == 0) ? acc0[r] : acc1[r];
            out[(((size_t)b * 256 + o) * 64 + ho) * 64 + woo] = v + biasl[o];
        }
    }
}

extern "C" void kernel_launch(void* const* d_in, const int* in_sizes, int n_in,
                              void* d_out, int out_size, void* d_ws, size_t ws_size,
                              hipStream_t stream) {
    const float* x      = (const float*)d_in[0];
    const float* weight = (const float*)d_in[1];
    const float* bias   = (const float*)d_in[2];
    const float* off_w  = (const float*)d_in[3];
    const float* off_b  = (const float*)d_in[4];
    const float* mask_w = (const float*)d_in[5];
    const float* mask_b = (const float*)d_in[6];
    float* out = (float*)d_out;

    float* ws_off = (float*)d_ws;                                      // 1,769,472 B
    unsigned short* ws_b  = (unsigned short*)((char*)d_ws + 1769472);  // 1,179,648 B
    unsigned short* ws_a2 = (unsigned short*)((char*)d_ws + 2949120);  //   147,456 B
    unsigned short* xt    = (unsigned short*)((char*)d_ws + 3096576);  // 8,388,608 B

    hipLaunchKernelGGL(weight_pack_kernel, dim3(100), dim3(256), 0, stream,
                       weight, off_w, mask_w, ws_b, ws_a2);
    hipLaunchKernelGGL(xpose_hwc_kernel, dim3(256), dim3(256), 0, stream,
                       x, xt);
    hipLaunchKernelGGL(offmask_mfma_kernel, dim3(256), dim3(512), 0, stream,
                       x, ws_a2, off_b, mask_b, ws_off);
    hipLaunchKernelGGL(deform_gemm_kernel, dim3(256), dim3(512), 0, stream,
                       xt, ws_off, ws_b, bias, out);
}

// Round 3
// 139.863 us; speedup vs baseline: 1.3228x; 1.1451x over previous
//
#include <hip/hip_runtime.h>
#include <hip/hip_bf16.h>
#include <string.h>

// DeformableConv2d: B=4, C=256, O=256, H=W=64, K=3, pad=1, stride=1
// Round 13: K3 software pipeline (scheduling-only change vs r12).
//   r12 post-mortem: coalescing worked (FETCH 17->10MB, -36us) but K3 is
//   still 80% idle at 2 waves/SIMD: two serial L2-latency chains per tap
//   (gather-wait before pack; 16 ua weight loads stalling one-by-one at
//   88 VGPR). Fix: (1) batch-preload all 16 ua uint4 into registers per
//   tap -> one amortized wait; (2) T14 split of the gather: issue tap
//   kk+1's corner loads BEFORE the MFMA halves, convert/pack AFTER, in two
//   2-pixel half-batches. vmcnt order (ua first, gathers after) keeps
//   gathers in flight across the MFMA section. Bilinear combine order,
//   bf16 pack, tile layout, MFMA K-order identical to r12 -> absmax
//   unchanged (0.0078125). VGPR ~88 -> ~180-200; still 2 waves/SIMD.
// K0, K1, K2 byte-identical to round 12.
// Workspace: ws_off 1769472 | ws_b 1179648 | ws_a2 147456 | xt 8388608
//          = 11,485,184 B.

typedef __attribute__((ext_vector_type(8))) short short8;
typedef __attribute__((ext_vector_type(8))) _Float16 half8;
typedef __attribute__((ext_vector_type(16))) float floatx16;

__device__ __forceinline__ unsigned bfbits(float f) {
    unsigned u;
    __builtin_memcpy(&u, &f, 4);
    return (u + 0x7fffu + ((u >> 16) & 1u)) >> 16;   // RNE f32->bf16
}
__device__ __forceinline__ unsigned pack_bf16(float lo, float hi) {
    return bfbits(lo) | (bfbits(hi) << 16);
}
__device__ __forceinline__ unsigned pack_f16(float lo, float hi) {
    _Float16 a = (_Float16)lo, b = (_Float16)hi;
    unsigned short ua, ub;
    __builtin_memcpy(&ua, &a, 2);
    __builtin_memcpy(&ub, &b, 2);
    return (unsigned)ua | ((unsigned)ub << 16);
}

// async global->LDS DMA, 4 B per lane; lane l's data lands at lds + l*4
__device__ __forceinline__ void gl_lds4(const float* g, float* l) {
    __builtin_amdgcn_global_load_lds(
        (const __attribute__((address_space(1))) unsigned int*)g,
        (__attribute__((address_space(3))) unsigned int*)l,
        4, 0, 0);
}

// ---------------------------------------------------------------------------
// K0: x (B,C,H,W) f32 -> xt (B,H,W,C) f16.  One block per (b, y) row.
// ---------------------------------------------------------------------------
__global__ __launch_bounds__(256) void xpose_hwc_kernel(
    const float* __restrict__ x, unsigned short* __restrict__ xt)
{
    __shared__ float stage[256 * 65];
    const int bid = blockIdx.x;          // (b*64 + y)
    const int b = bid >> 6, y = bid & 63;
    const int tid = threadIdx.x;
    const float* src = x + (size_t)b * 256 * 4096 + y * 64;

#pragma unroll
    for (int i = 0; i < 16; ++i) {
        int idx = i * 256 + tid;         // 0..4095 = (c, xq)
        int c = idx >> 4, xq = idx & 15;
        float4 v = *(const float4*)&src[(size_t)c * 4096 + xq * 4];
        stage[c * 65 + xq * 4 + 0] = v.x;
        stage[c * 65 + xq * 4 + 1] = v.y;
        stage[c * 65 + xq * 4 + 2] = v.z;
        stage[c * 65 + xq * 4 + 3] = v.w;
    }
    __syncthreads();

    unsigned short* dst = xt + (size_t)bid * 16384;   // 64 px * 256 ch
#pragma unroll
    for (int i = 0; i < 32; ++i) {
        int c2 = (tid & 127) * 2;
        int xx = i * 2 + (tid >> 7);
        float f0 = stage[c2 * 65 + xx];
        float f1 = stage[(c2 + 1) * 65 + xx];
        *(unsigned*)&dst[xx * 256 + c2] = pack_f16(f0, f1);
    }
}

// ---------------------------------------------------------------------------
// K1: weight pack (verbatim rounds 4-12).
// ---------------------------------------------------------------------------
__global__ __launch_bounds__(256) void weight_pack_kernel(
    const float* __restrict__ w, const float* __restrict__ off_w,
    const float* __restrict__ mask_w,
    unsigned short* __restrict__ ws_b, unsigned short* __restrict__ ws_a2)
{
    __shared__ float slab[32 * 289];
    const int bid = blockIdx.x;
    const int tid = threadIdx.x;

    if (bid < 64) {
        const int nt = bid >> 3, cb = bid & 7;
        const float* wbase = w + (size_t)nt * 32 * 2304 + cb * 288;
#pragma unroll
        for (int i = 0; i < 9; ++i) {
            int idx = i * 256 + tid;               // 0..2303
            int o = idx / 72, f4 = idx % 72;
            float4 v = *(const float4*)&wbase[(size_t)o * 2304 + f4 * 4];
            slab[o * 289 + f4 * 4 + 0] = v.x;
            slab[o * 289 + f4 * 4 + 1] = v.y;
            slab[o * 289 + f4 * 4 + 2] = v.z;
            slab[o * 289 + f4 * 4 + 3] = v.w;
        }
        __syncthreads();
#pragma unroll
        for (int pass = 0; pass < 5; ++pass) {
            int rid = pass * 8 + (tid >> 5);
            if (rid < 36) {
                int kk = rid >> 2, q = rid & 3;
                int no = tid & 31;
                unsigned pk[4];
#pragma unroll
                for (int i = 0; i < 4; ++i) {
                    float f0 = slab[no * 289 + (q * 8 + 2 * i) * 9 + kk];
                    float f1 = slab[no * 289 + (q * 8 + 2 * i + 1) * 9 + kk];
                    pk[i] = pack_bf16(f0, f1);
                }
                size_t u = ((size_t)nt * 288 + kk * 32 + cb * 4 + q) * 32 + no;
                *(uint4*)&ws_b[u * 8] = make_uint4(pk[0], pk[1], pk[2], pk[3]);
            }
        }
    } else {
        int e = (bid - 64) * 256 + tid;       // 0..9215
        int lan = e & 31;                     // oc row
        int ku = e >> 5;                      // 0..287
        int kk = ku >> 5;
        int c0 = (ku & 31) * 8;
        int o = lan;
        float f[8];
#pragma unroll
        for (int j = 0; j < 8; ++j) {
            int c = c0 + j;
            float v = 0.f;
            if (o < 18)      v = off_w[((size_t)o * 256 + c) * 9 + kk];
            else if (o < 27) v = mask_w[((size_t)(o - 18) * 256 + c) * 9 + kk];
            f[j] = v;
        }
        unsigned pk[4];
#pragma unroll
        for (int i = 0; i < 4; ++i) pk[i] = pack_f16(f[2 * i], f[2 * i + 1]);
        *(uint4*)&ws_a2[(size_t)e * 8] = make_uint4(pk[0], pk[1], pk[2], pk[3]);
    }
}

// ---------------------------------------------------------------------------
// K2: offset/mask conv via f16 MFMA with global_load_lds staging
// (verbatim rounds 9-12).
// ---------------------------------------------------------------------------
__global__ __launch_bounds__(512) void offmask_mfma_kernel(
    const float* __restrict__ x, const unsigned short* __restrict__ ws_a2,
    const float* __restrict__ off_b, const float* __restrict__ mask_b,
    float* __restrict__ ws_off)
{
    __shared__ float stage[256 * 64];     // 64 KiB: x[.][hh][.] for one row
    __shared__ uint4 bufB[2][2048];       // 64 KiB; aliased as red[] in epilogue
    const int bid = blockIdx.x;
    const int row = (bid & 7) * 32 + (bid >> 3);
    const int b = row >> 6, ho = row & 63;
    const int tid = threadIdx.x;
    const int l = tid & 63;
    const int w = tid >> 6;
    const int lan = l & 31, h = l >> 5;
    const float* xb = x + (size_t)b * 256 * 4096;

    floatx16 acc;
#pragma unroll
    for (int r = 0; r < 16; ++r) acc[r] = 0.f;

    const int n = l;                 // pixel within row
    const int ku0 = w;               // 0..7
    const int ntile = w >> 2, kq = w & 3;

    auto stage_row = [&](int hh) {
        if (hh >= 0 && hh < 64) {
            const float* src = xb + hh * 64;
#pragma unroll
            for (int i = 0; i < 32; ++i) {
                int c = w * 32 + i;                 // wave-uniform channel
                gl_lds4(src + (size_t)c * 4096 + l, &stage[c * 64]);
            }
        } else {
#pragma unroll
            for (int i = 0; i < 32; ++i) {
                int c = w * 32 + i;
                stage[c * 64 + l] = 0.f;
            }
        }
    };

    auto build = [&](int kk, int kx) {
        int px = n - 1 + kx;
        bool vx = (px >= 0 && px < 64);
        int pxc = vx ? px : 0;
        int buf = kk & 1;
#pragma unroll
        for (int j = 0; j < 4; ++j) {
            int ku = ku0 + 8 * j;
            int c0 = ku * 8;
            float v[8];
#pragma unroll
            for (int jj = 0; jj < 8; ++jj) {
                float t = stage[(c0 + jj) * 64 + pxc];
                v[jj] = vx ? t : 0.f;
            }
            unsigned pk[4];
#pragma unroll
            for (int i = 0; i < 4; ++i) pk[i] = pack_f16(v[2 * i], v[2 * i + 1]);
            bufB[buf][ku * 64 + n] = make_uint4(pk[0], pk[1], pk[2], pk[3]);
        }
    };

    auto domfma = [&](int kk) {
        int buf = kk & 1;
        const uint4* a4 = (const uint4*)ws_a2;
#pragma unroll
        for (int s4 = 0; s4 < 4; ++s4) {
            int s = kq * 4 + s4;         // K-step 0..15 within chunk
            int kul = s * 2 + h;         // local ku 0..31
            uint4 ua = a4[(size_t)(kk * 32 + kul) * 32 + lan];
            uint4 ub = bufB[buf][kul * 64 + ntile * 32 + lan];
            half8 a, bb;
            __builtin_memcpy(&a, &ua, 16);
            __builtin_memcpy(&bb, &ub, 16);
            acc = __builtin_amdgcn_mfma_f32_32x32x16_f16(a, bb, acc, 0, 0, 0);
        }
    };

    for (int ky = 0; ky < 3; ++ky) {
        __syncthreads();                 // prior builds done reading stage
        stage_row(ho - 1 + ky);
        __syncthreads();                 // DMA drained (vmcnt(0) before barrier)
#pragma unroll
        for (int kx = 0; kx < 3; ++kx) {
            int kk = ky * 3 + kx;
            build(kk, kx);
            __syncthreads();
            domfma(kk);
        }
    }
    __syncthreads();                     // last domfma done before red alias

    // cross-wave partial-C reduction (4 K-quarters per n-tile) - verbatim
    float* red = (float*)bufB;           // 8 waves x 64 lanes x 16 = 32 KiB
#pragma unroll
    for (int r = 0; r < 16; ++r) red[(w * 64 + l) * 16 + r] = acc[r];
    __syncthreads();
    for (int idx = tid; idx < 27 * 64; idx += 512) {
        int oc = idx >> 6, wo = idx & 63;
        int nt2 = wo >> 5, nn = wo & 31;
        int h2 = (oc >> 2) & 1;
        int r = (oc & 3) | ((oc >> 3) << 2);
        int lane2 = nn + 32 * h2;
        float s = 0.f;
#pragma unroll
        for (int kq2 = 0; kq2 < 4; ++kq2)
            s += red[((nt2 * 4 + kq2) * 64 + lane2) * 16 + r];
        float v;
        if (oc < 18) {
            v = s + off_b[oc];
        } else {
            float t = s + mask_b[oc - 18];
            v = 1.f / (1.f + expf(-t));
        }
        ws_off[(size_t)row * 1728 + idx] = v;
    }
}

// ---------------------------------------------------------------------------
// K3: fused deformable sampling + GEMM, software-pipelined.
// 256 blocks, 512 threads / 8 waves, 64 px/block.  Per tap:
//   preload 16 ua weight uint4 (regs) -> issue gathers(kk+1) halfA ->
//   MFMA ks0..7 -> pack halfA + issue halfB -> MFMA ks8..15 -> pack halfB
//   -> barrier.  Same arithmetic/order as r12.
// ---------------------------------------------------------------------------
__global__ __launch_bounds__(512) void deform_gemm_kernel(
    const unsigned short* __restrict__ xt, const float* __restrict__ ws_off,
    const unsigned short* __restrict__ ws_b, const float* __restrict__ bias,
    float* __restrict__ out)
{
    __shared__ float params[576 * 8];   // per (tap,px): 4 weights + 4 byte-offsets
    __shared__ float biasl[256];
    __shared__ uint4 tile[2][2048];     // [buf][ku(32)*64 + n], XOR-swizzled

    const int bid = blockIdx.x;
    const int row = (bid & 7) * 32 + (bid >> 3);
    const int b = row >> 6, ho = row & 63;
    const int tid = threadIdx.x;
    const int l = tid & 63;
    const int wid = tid >> 6;          // 0..7
    const int lan = l & 31;            // channel-group (producer) / MFMA lane
    const int h = l >> 5;              // pixel-parity (producer) / MFMA K-half

    if (tid < 256) biasl[tid] = bias[tid];

    // ---- per-(tap,pixel) sampling params: weights + clamped corner offsets
    {
        const float* ob = ws_off + (size_t)row * 1728;
        for (int it = tid; it < 576; it += 512) {
            int kk = it >> 6, p = it & 63;
            float dy = ob[(2 * kk) * 64 + p];
            float dx = ob[(2 * kk + 1) * 64 + p];
            float mk = ob[(18 + kk) * 64 + p];
            int ky = kk / 3, kx = kk - ky * 3;
            float py = (float)(ho - 1 + ky) + dy;
            float px = (float)(p - 1 + kx) + dx;
            float y0f = floorf(py), x0f = floorf(px);
            float wy1 = py - y0f, wx1 = px - x0f;
            float wy0 = 1.f - wy1, wx0 = 1.f - wx1;
            int y0 = (int)y0f, xi0 = (int)x0f;
            int y1 = y0 + 1, xi1 = xi0 + 1;
            float vy0 = (y0 >= 0 && y0 < 64) ? 1.f : 0.f;
            float vy1 = (y1 >= 0 && y1 < 64) ? 1.f : 0.f;
            float vx0 = (xi0 >= 0 && xi0 < 64) ? 1.f : 0.f;
            float vx1 = (xi1 >= 0 && xi1 < 64) ? 1.f : 0.f;
            float wr0 = wy0 * vy0 * mk, wr1 = wy1 * vy1 * mk;
            float wa = wx0 * vx0, wb2 = wx1 * vx1;
            int yc0 = min(max(y0, 0), 63), yc1 = min(max(y1, 0), 63);
            int xc0 = min(max(xi0, 0), 63), xc1 = min(max(xi1, 0), 63);
            float* pr = &params[it * 8];
            pr[0] = wr0 * wa;  pr[1] = wr0 * wb2;
            pr[2] = wr1 * wa;  pr[3] = wr1 * wb2;
            pr[4] = __int_as_float((yc0 * 64 + xc0) << 9);   // *512 B
            pr[5] = __int_as_float((yc0 * 64 + xc1) << 9);
            pr[6] = __int_as_float((yc1 * 64 + xc0) << 9);
            pr[7] = __int_as_float((yc1 * 64 + xc1) << 9);
        }
    }
    __syncthreads();

    const char* xb16 = (const char*)xt + ((size_t)b << 21);   // b * 2 MiB
    const uint4* wb4 = (const uint4*)ws_b;

    floatx16 acc0, acc1;
#pragma unroll
    for (int r = 0; r < 16; ++r) { acc0[r] = 0.f; acc1[r] = 0.f; }

    // pipeline register state: 2-pixel gather half-batches
    uint4 gA[2][4], gB[2][4];
    float4 wvA[2], wvB[2];
    uint4 ua[16];

    auto issue_half = [&](int kk, int i0, uint4 (&g)[2][4], float4 (&wv)[2]) {
#pragma unroll
        for (int i = 0; i < 2; ++i) {
            int p = wid * 8 + 2 * (i0 + i) + h;
            const float* pr = &params[(kk * 64 + p) * 8];
            __builtin_memcpy(&wv[i], pr, 16);
            int4 ov;
            __builtin_memcpy(&ov, pr + 4, 16);
            __builtin_memcpy(&g[i][0], xb16 + ov.x + (lan << 4), 16);
            __builtin_memcpy(&g[i][1], xb16 + ov.y + (lan << 4), 16);
            __builtin_memcpy(&g[i][2], xb16 + ov.z + (lan << 4), 16);
            __builtin_memcpy(&g[i][3], xb16 + ov.w + (lan << 4), 16);
        }
    };

    auto pack_half = [&](int buf, int i0, uint4 (&g)[2][4], float4 (&wv)[2]) {
        char* tb = (char*)&tile[buf][0];
#pragma unroll
        for (int i = 0; i < 2; ++i) {
            int p = wid * 8 + 2 * (i0 + i) + h;
            half8 h00, h01, h10, h11;
            __builtin_memcpy(&h00, &g[i][0], 16);
            __builtin_memcpy(&h01, &g[i][1], 16);
            __builtin_memcpy(&h10, &g[i][2], 16);
            __builtin_memcpy(&h11, &g[i][3], 16);
            unsigned pk[4];
#pragma unroll
            for (int j = 0; j < 4; ++j) {
                float v0 = wv[i].x * (float)h00[2 * j]     + wv[i].y * (float)h01[2 * j]
                         + wv[i].z * (float)h10[2 * j]     + wv[i].w * (float)h11[2 * j];
                float v1 = wv[i].x * (float)h00[2 * j + 1] + wv[i].y * (float)h01[2 * j + 1]
                         + wv[i].z * (float)h10[2 * j + 1] + wv[i].w * (float)h11[2 * j + 1];
                pk[j] = pack_bf16(v0, v1);
            }
            uint4 wv4 = make_uint4(pk[0], pk[1], pk[2], pk[3]);
            __builtin_memcpy(tb + lan * 1024 + ((p << 4) ^ (lan << 4)), &wv4, 16);
        }
    };

    // prologue: build tile[0] for tap 0
    issue_half(0, 0, gA, wvA);
    pack_half(0, 0, gA, wvA);
    issue_half(0, 2, gB, wvB);
    pack_half(0, 2, gB, wvB);
    __syncthreads();

    for (int kk = 0; kk < 9; ++kk) {
        const int buf = kk & 1, nbuf = (kk + 1) & 1;

        // batch-preload this tap's weight fragments (issued before gathers,
        // so the MFMA halves can wait on ua while gathers stay in flight)
#pragma unroll
        for (int ks = 0; ks < 16; ++ks) {
            int kul = ks * 2 + h;
            ua[ks] = wb4[((size_t)wid * 288 + kk * 32 + kul) * 32 + lan];
        }
        if (kk < 8) issue_half(kk + 1, 0, gA, wvA);

        {   // MFMA ks 0..7
            const char* tb = (const char*)&tile[buf][0];
#pragma unroll
            for (int ks = 0; ks < 8; ++ks) {
                int kul = ks * 2 + h;
                uint4 ub0, ub1;
                __builtin_memcpy(&ub0, tb + kul * 1024 + ((lan << 4) ^ (kul << 4)), 16);
                __builtin_memcpy(&ub1, tb + kul * 1024 + (((32 + lan) << 4) ^ (kul << 4)), 16);
                short8 a, b0, b1;
                __builtin_memcpy(&a, &ua[ks], 16);
                __builtin_memcpy(&b0, &ub0, 16);
                __builtin_memcpy(&b1, &ub1, 16);
                acc0 = __builtin_amdgcn_mfma_f32_32x32x16_bf16(a, b0, acc0, 0, 0, 0);
                acc1 = __builtin_amdgcn_mfma_f32_32x32x16_bf16(a, b1, acc1, 0, 0, 0);
            }
        }

        if (kk < 8) {
            pack_half(nbuf, 0, gA, wvA);
            issue_half(kk + 1, 2, gB, wvB);
        }

        {   // MFMA ks 8..15
            const char* tb = (const char*)&tile[buf][0];
#pragma unroll
            for (int ks = 8; ks < 16; ++ks) {
                int kul = ks * 2 + h;
                uint4 ub0, ub1;
                __builtin_memcpy(&ub0, tb + kul * 1024 + ((lan << 4) ^ (kul << 4)), 16);
                __builtin_memcpy(&ub1, tb + kul * 1024 + (((32 + lan) << 4) ^ (kul << 4)), 16);
                short8 a, b0, b1;
                __builtin_memcpy(&a, &ua[ks], 16);
                __builtin_memcpy(&b0, &ub0, 16);
                __builtin_memcpy(&b1, &ub1, 16);
                acc0 = __builtin_amdgcn_mfma_f32_32x32x16_bf16(a, b0, acc0, 0, 0, 0);
                acc1 = __builtin_amdgcn_mfma_f32_32x32x16_bf16(a, b1, acc1, 0, 0, 0);
            }
        }

        if (kk < 8) pack_half(nbuf, 2, gB, wvB);
        __syncthreads();
    }

    // epilogue: wave wid owns m-tile wid, 2 n-tiles (verbatim)
#pragma unroll
    for (int nt = 0; nt < 2; ++nt) {
#pragma unroll
        for (int r = 0; r < 16; ++r) {
            int o = wid * 32 + (r & 3) + 8 * (r >> 2) + 4 * h;
            int woo = nt * 32 + lan;
            float v = (nt == 0) ? acc0[r] : acc1[r];
            out[(((size_t)b * 256 + o) * 64 + ho) * 64 + woo] = v + biasl[o];
        }
    }
}

extern "C" void kernel_launch(void* const* d_in, const int* in_sizes, int n_in,
                              void* d_out, int out_size, void* d_ws, size_t ws_size,
                              hipStream_t stream) {
    const float* x      = (const float*)d_in[0];
    const float* weight = (const float*)d_in[1];
    const float* bias   = (const float*)d_in[2];
    const float* off_w  = (const float*)d_in[3];
    const float* off_b  = (const float*)d_in[4];
    const float* mask_w = (const float*)d_in[5];
    const float* mask_b = (const float*)d_in[6];
    float* out = (float*)d_out;

    float* ws_off = (float*)d_ws;                                      // 1,769,472 B
    unsigned short* ws_b  = (unsigned short*)((char*)d_ws + 1769472);  // 1,179,648 B
    unsigned short* ws_a2 = (unsigned short*)((char*)d_ws + 2949120);  //   147,456 B
    unsigned short* xt    = (unsigned short*)((char*)d_ws + 3096576);  // 8,388,608 B

    hipLaunchKernelGGL(weight_pack_kernel, dim3(100), dim3(256), 0, stream,
                       weight, off_w, mask_w, ws_b, ws_a2);
    hipLaunchKernelGGL(xpose_hwc_kernel, dim3(256), dim3(256), 0, stream,
                       x, xt);
    hipLaunchKernelGGL(offmask_mfma_kernel, dim3(256), dim3(512), 0, stream,
                       x, ws_a2, off_b, mask_b, ws_off);
    hipLaunchKernelGGL(deform_gemm_kernel, dim3(256), dim3(512), 0, stream,
                       xt, ws_off, ws_b, bias, out);
}

// Round 4
// 132.290 us; speedup vs baseline: 1.3986x; 1.0572x over previous
//
#include <hip/hip_runtime.h>
#include <hip/hip_bf16.h>
#include <string.h>

// DeformableConv2d: B=4, C=256, O=256, H=W=64, K=3, pad=1, stride=1
// Round 14: K2 rewrite to consume xt (one change vs r13).
//   r13 post-mortem: K3 pipelining landed as predicted (64.6->44.4us).
//   Remaining controllable chunk: K2 (~35-40us by subtraction), untouched
//   since r9. It staged x as f32 via width-4 global_load_lds, then did a
//   per-tap build() (32 scalar ds_reads + 16 pack_f16 per thread) and 3
//   barriers per tap. New K2: stage 3 rows of xt (f16 HWC, 32KB each) via
//   width-16 global_load_lds with write-side XOR swizzle (granule ^= px&7),
//   ONE barrier, then MFMA B-fragments are direct 16B ds_reads at
//   (row, px=n+kx, kul) -- the build phase vanishes; barriers 29 -> 3.
//   Same f16 values (xt = identical pack_f16 of the same f32), same zero
//   padding, same accumulate order (tap 0..8 x s4 0..3, kq/ntile split,
//   f32 reduction) -> ws_off bit-identical, absmax stays 0.0078125.
// K0, K1, K3 byte-identical to round 13.
// Workspace: ws_off 1769472 | ws_b 1179648 | ws_a2 147456 | xt 8388608
//          = 11,485,184 B.

typedef __attribute__((ext_vector_type(8))) short short8;
typedef __attribute__((ext_vector_type(8))) _Float16 half8;
typedef __attribute__((ext_vector_type(16))) float floatx16;

__device__ __forceinline__ unsigned bfbits(float f) {
    unsigned u;
    __builtin_memcpy(&u, &f, 4);
    return (u + 0x7fffu + ((u >> 16) & 1u)) >> 16;   // RNE f32->bf16
}
__device__ __forceinline__ unsigned pack_bf16(float lo, float hi) {
    return bfbits(lo) | (bfbits(hi) << 16);
}
__device__ __forceinline__ unsigned pack_f16(float lo, float hi) {
    _Float16 a = (_Float16)lo, b = (_Float16)hi;
    unsigned short ua, ub;
    __builtin_memcpy(&ua, &a, 2);
    __builtin_memcpy(&ub, &b, 2);
    return (unsigned)ua | ((unsigned)ub << 16);
}

// async global->LDS DMA, 16 B per lane; lane l's data lands at lds + l*16.
// Global source address is PER-LANE (enables write-side swizzle).
__device__ __forceinline__ void gl_lds16(const void* g, void* l) {
    __builtin_amdgcn_global_load_lds(
        (const __attribute__((address_space(1))) unsigned int*)g,
        (__attribute__((address_space(3))) unsigned int*)l,
        16, 0, 0);
}

// ---------------------------------------------------------------------------
// K0: x (B,C,H,W) f32 -> xt (B,H,W,C) f16.  One block per (b, y) row.
// (verbatim round 12-13)
// ---------------------------------------------------------------------------
__global__ __launch_bounds__(256) void xpose_hwc_kernel(
    const float* __restrict__ x, unsigned short* __restrict__ xt)
{
    __shared__ float stage[256 * 65];
    const int bid = blockIdx.x;          // (b*64 + y)
    const int b = bid >> 6, y = bid & 63;
    const int tid = threadIdx.x;
    const float* src = x + (size_t)b * 256 * 4096 + y * 64;

#pragma unroll
    for (int i = 0; i < 16; ++i) {
        int idx = i * 256 + tid;         // 0..4095 = (c, xq)
        int c = idx >> 4, xq = idx & 15;
        float4 v = *(const float4*)&src[(size_t)c * 4096 + xq * 4];
        stage[c * 65 + xq * 4 + 0] = v.x;
        stage[c * 65 + xq * 4 + 1] = v.y;
        stage[c * 65 + xq * 4 + 2] = v.z;
        stage[c * 65 + xq * 4 + 3] = v.w;
    }
    __syncthreads();

    unsigned short* dst = xt + (size_t)bid * 16384;   // 64 px * 256 ch
#pragma unroll
    for (int i = 0; i < 32; ++i) {
        int c2 = (tid & 127) * 2;
        int xx = i * 2 + (tid >> 7);
        float f0 = stage[c2 * 65 + xx];
        float f1 = stage[(c2 + 1) * 65 + xx];
        *(unsigned*)&dst[xx * 256 + c2] = pack_f16(f0, f1);
    }
}

// ---------------------------------------------------------------------------
// K1: weight pack (verbatim rounds 4-13).
// ---------------------------------------------------------------------------
__global__ __launch_bounds__(256) void weight_pack_kernel(
    const float* __restrict__ w, const float* __restrict__ off_w,
    const float* __restrict__ mask_w,
    unsigned short* __restrict__ ws_b, unsigned short* __restrict__ ws_a2)
{
    __shared__ float slab[32 * 289];
    const int bid = blockIdx.x;
    const int tid = threadIdx.x;

    if (bid < 64) {
        const int nt = bid >> 3, cb = bid & 7;
        const float* wbase = w + (size_t)nt * 32 * 2304 + cb * 288;
#pragma unroll
        for (int i = 0; i < 9; ++i) {
            int idx = i * 256 + tid;               // 0..2303
            int o = idx / 72, f4 = idx % 72;
            float4 v = *(const float4*)&wbase[(size_t)o * 2304 + f4 * 4];
            slab[o * 289 + f4 * 4 + 0] = v.x;
            slab[o * 289 + f4 * 4 + 1] = v.y;
            slab[o * 289 + f4 * 4 + 2] = v.z;
            slab[o * 289 + f4 * 4 + 3] = v.w;
        }
        __syncthreads();
#pragma unroll
        for (int pass = 0; pass < 5; ++pass) {
            int rid = pass * 8 + (tid >> 5);
            if (rid < 36) {
                int kk = rid >> 2, q = rid & 3;
                int no = tid & 31;
                unsigned pk[4];
#pragma unroll
                for (int i = 0; i < 4; ++i) {
                    float f0 = slab[no * 289 + (q * 8 + 2 * i) * 9 + kk];
                    float f1 = slab[no * 289 + (q * 8 + 2 * i + 1) * 9 + kk];
                    pk[i] = pack_bf16(f0, f1);
                }
                size_t u = ((size_t)nt * 288 + kk * 32 + cb * 4 + q) * 32 + no;
                *(uint4*)&ws_b[u * 8] = make_uint4(pk[0], pk[1], pk[2], pk[3]);
            }
        }
    } else {
        int e = (bid - 64) * 256 + tid;       // 0..9215
        int lan = e & 31;                     // oc row
        int ku = e >> 5;                      // 0..287
        int kk = ku >> 5;
        int c0 = (ku & 31) * 8;
        int o = lan;
        float f[8];
#pragma unroll
        for (int j = 0; j < 8; ++j) {
            int c = c0 + j;
            float v = 0.f;
            if (o < 18)      v = off_w[((size_t)o * 256 + c) * 9 + kk];
            else if (o < 27) v = mask_w[((size_t)(o - 18) * 256 + c) * 9 + kk];
            f[j] = v;
        }
        unsigned pk[4];
#pragma unroll
        for (int i = 0; i < 4; ++i) pk[i] = pack_f16(f[2 * i], f[2 * i + 1]);
        *(uint4*)&ws_a2[(size_t)e * 8] = make_uint4(pk[0], pk[1], pk[2], pk[3]);
    }
}

// ---------------------------------------------------------------------------
// K2: offset/mask conv, xt-direct edition.  256 blocks x 512 thr / 8 waves.
// Stage 3 f16 HWC rows (66 px incl. zero pads, XOR-swizzled granules) via
// width-16 global_load_lds; ONE barrier; 36 MFMAs/wave reading B directly
// from LDS; cross-wave f32 reduction (verbatim r9).
// ---------------------------------------------------------------------------
__global__ __launch_bounds__(512) void offmask_mfma_kernel(
    const unsigned short* __restrict__ xt, const unsigned short* __restrict__ ws_a2,
    const float* __restrict__ off_b, const float* __restrict__ mask_b,
    float* __restrict__ ws_off)
{
    // [row r][p01 0..65][granule j 0..31] of 16B; logical kul at j = kul^(p01&7)
    __shared__ uint4 stage[3 * 66 * 32];      // 101,376 B; aliased as red[]
    const int bid = blockIdx.x;
    const int row = (bid & 7) * 32 + (bid >> 3);
    const int b = row >> 6, ho = row & 63;
    const int tid = threadIdx.x;
    const int l = tid & 63;
    const int w = tid >> 6;
    const int lan = l & 31, h = l >> 5;
    const int ntile = w >> 2, kq = w & 3;

    // ---- stage 3 input rows ----
    const char* xtb = (const char*)xt + (size_t)b * 64 * 32768;
    for (int r = 0; r < 3; ++r) {
        int y = ho - 1 + r;
        uint4* rowbase = &stage[r * 66 * 32];
        if (y >= 0 && y < 64) {
            const char* src = xtb + (size_t)y * 32768;
            // interior granules 32..2079 (p01 1..64): 32 chunks of 64;
            // wave w stages chunks w*4 .. w*4+3 (dest wave-uniform+lane*16)
#pragma unroll
            for (int i = 0; i < 4; ++i) {
                int g0 = 32 + (w * 4 + i) * 64;
                int g = g0 + l;
                int p01 = g >> 5, j = g & 31;
                int kul = j ^ (p01 & 7);
                gl_lds16(src + ((size_t)(p01 - 1) * 32 + kul) * 16,
                         rowbase + g0);
            }
            // zero pads p01=0 (granules 0..31) and p01=65 (2080..2111)
            if (tid < 64) {
                int g = (tid < 32) ? tid : (2080 + (tid - 32));
                rowbase[g] = make_uint4(0, 0, 0, 0);
            }
        } else {
            for (int g = tid; g < 2112; g += 512)
                rowbase[g] = make_uint4(0, 0, 0, 0);
        }
    }
    __syncthreads();                  // DMA drained; stage complete

    floatx16 acc;
#pragma unroll
    for (int r = 0; r < 16; ++r) acc[r] = 0.f;

    const uint4* a4 = (const uint4*)ws_a2;
    const int n = ntile * 32 + lan;   // output pixel for this lane
#pragma unroll
    for (int ky = 0; ky < 3; ++ky) {
#pragma unroll
        for (int kx = 0; kx < 3; ++kx) {
            int kk = ky * 3 + kx;
            int p01 = n + kx;
#pragma unroll
            for (int s4 = 0; s4 < 4; ++s4) {
                int s = kq * 4 + s4;          // K-step 0..15 within chunk
                int kul = s * 2 + h;          // local ku 0..31
                uint4 ua = a4[(size_t)(kk * 32 + kul) * 32 + lan];
                uint4 ub = stage[(ky * 66 + p01) * 32 + (kul ^ (p01 & 7))];
                half8 a, bb;
                __builtin_memcpy(&a, &ua, 16);
                __builtin_memcpy(&bb, &ub, 16);
                acc = __builtin_amdgcn_mfma_f32_32x32x16_f16(a, bb, acc, 0, 0, 0);
            }
        }
    }
    __syncthreads();                  // all waves done reading stage

    // cross-wave partial-C reduction (4 K-quarters per n-tile) - verbatim r9
    float* red = (float*)stage;       // 8 waves x 64 lanes x 16 = 32 KiB
#pragma unroll
    for (int r = 0; r < 16; ++r) red[(w * 64 + l) * 16 + r] = acc[r];
    __syncthreads();
    for (int idx = tid; idx < 27 * 64; idx += 512) {
        int oc = idx >> 6, wo = idx & 63;
        int nt2 = wo >> 5, nn = wo & 31;
        int h2 = (oc >> 2) & 1;
        int r = (oc & 3) | ((oc >> 3) << 2);
        int lane2 = nn + 32 * h2;
        float s = 0.f;
#pragma unroll
        for (int kq2 = 0; kq2 < 4; ++kq2)
            s += red[((nt2 * 4 + kq2) * 64 + lane2) * 16 + r];
        float v;
        if (oc < 18) {
            v = s + off_b[oc];
        } else {
            float t = s + mask_b[oc - 18];
            v = 1.f / (1.f + expf(-t));
        }
        ws_off[(size_t)row * 1728 + idx] = v;
    }
}

// ---------------------------------------------------------------------------
// K3: fused deformable sampling + GEMM, software-pipelined (verbatim r13).
// ---------------------------------------------------------------------------
__global__ __launch_bounds__(512) void deform_gemm_kernel(
    const unsigned short* __restrict__ xt, const float* __restrict__ ws_off,
    const unsigned short* __restrict__ ws_b, const float* __restrict__ bias,
    float* __restrict__ out)
{
    __shared__ float params[576 * 8];   // per (tap,px): 4 weights + 4 byte-offsets
    __shared__ float biasl[256];
    __shared__ uint4 tile[2][2048];     // [buf][ku(32)*64 + n], XOR-swizzled

    const int bid = blockIdx.x;
    const int row = (bid & 7) * 32 + (bid >> 3);
    const int b = row >> 6, ho = row & 63;
    const int tid = threadIdx.x;
    const int l = tid & 63;
    const int wid = tid >> 6;          // 0..7
    const int lan = l & 31;            // channel-group (producer) / MFMA lane
    const int h = l >> 5;              // pixel-parity (producer) / MFMA K-half

    if (tid < 256) biasl[tid] = bias[tid];

    // ---- per-(tap,pixel) sampling params: weights + clamped corner offsets
    {
        const float* ob = ws_off + (size_t)row * 1728;
        for (int it = tid; it < 576; it += 512) {
            int kk = it >> 6, p = it & 63;
            float dy = ob[(2 * kk) * 64 + p];
            float dx = ob[(2 * kk + 1) * 64 + p];
            float mk = ob[(18 + kk) * 64 + p];
            int ky = kk / 3, kx = kk - ky * 3;
            float py = (float)(ho - 1 + ky) + dy;
            float px = (float)(p - 1 + kx) + dx;
            float y0f = floorf(py), x0f = floorf(px);
            float wy1 = py - y0f, wx1 = px - x0f;
            float wy0 = 1.f - wy1, wx0 = 1.f - wx1;
            int y0 = (int)y0f, xi0 = (int)x0f;
            int y1 = y0 + 1, xi1 = xi0 + 1;
            float vy0 = (y0 >= 0 && y0 < 64) ? 1.f : 0.f;
            float vy1 = (y1 >= 0 && y1 < 64) ? 1.f : 0.f;
            float vx0 = (xi0 >= 0 && xi0 < 64) ? 1.f : 0.f;
            float vx1 = (xi1 >= 0 && xi1 < 64) ? 1.f : 0.f;
            float wr0 = wy0 * vy0 * mk, wr1 = wy1 * vy1 * mk;
            float wa = wx0 * vx0, wb2 = wx1 * vx1;
            int yc0 = min(max(y0, 0), 63), yc1 = min(max(y1, 0), 63);
            int xc0 = min(max(xi0, 0), 63), xc1 = min(max(xi1, 0), 63);
            float* pr = &params[it * 8];
            pr[0] = wr0 * wa;  pr[1] = wr0 * wb2;
            pr[2] = wr1 * wa;  pr[3] = wr1 * wb2;
            pr[4] = __int_as_float((yc0 * 64 + xc0) << 9);   // *512 B
            pr[5] = __int_as_float((yc0 * 64 + xc1) << 9);
            pr[6] = __int_as_float((yc1 * 64 + xc0) << 9);
            pr[7] = __int_as_float((yc1 * 64 + xc1) << 9);
        }
    }
    __syncthreads();

    const char* xb16 = (const char*)xt + ((size_t)b << 21);   // b * 2 MiB
    const uint4* wb4 = (const uint4*)ws_b;

    floatx16 acc0, acc1;
#pragma unroll
    for (int r = 0; r < 16; ++r) { acc0[r] = 0.f; acc1[r] = 0.f; }

    // pipeline register state: 2-pixel gather half-batches
    uint4 gA[2][4], gB[2][4];
    float4 wvA[2], wvB[2];
    uint4 ua[16];

    auto issue_half = [&](int kk, int i0, uint4 (&g)[2][4], float4 (&wv)[2]) {
#pragma unroll
        for (int i = 0; i < 2; ++i) {
            int p = wid * 8 + 2 * (i0 + i) + h;
            const float* pr = &params[(kk * 64 + p) * 8];
            __builtin_memcpy(&wv[i], pr, 16);
            int4 ov;
            __builtin_memcpy(&ov, pr + 4, 16);
            __builtin_memcpy(&g[i][0], xb16 + ov.x + (lan << 4), 16);
            __builtin_memcpy(&g[i][1], xb16 + ov.y + (lan << 4), 16);
            __builtin_memcpy(&g[i][2], xb16 + ov.z + (lan << 4), 16);
            __builtin_memcpy(&g[i][3], xb16 + ov.w + (lan << 4), 16);
        }
    };

    auto pack_half = [&](int buf, int i0, uint4 (&g)[2][4], float4 (&wv)[2]) {
        char* tb = (char*)&tile[buf][0];
#pragma unroll
        for (int i = 0; i < 2; ++i) {
            int p = wid * 8 + 2 * (i0 + i) + h;
            half8 h00, h01, h10, h11;
            __builtin_memcpy(&h00, &g[i][0], 16);
            __builtin_memcpy(&h01, &g[i][1], 16);
            __builtin_memcpy(&h10, &g[i][2], 16);
            __builtin_memcpy(&h11, &g[i][3], 16);
            unsigned pk[4];
#pragma unroll
            for (int j = 0; j < 4; ++j) {
                float v0 = wv[i].x * (float)h00[2 * j]     + wv[i].y * (float)h01[2 * j]
                         + wv[i].z * (float)h10[2 * j]     + wv[i].w * (float)h11[2 * j];
                float v1 = wv[i].x * (float)h00[2 * j + 1] + wv[i].y * (float)h01[2 * j + 1]
                         + wv[i].z * (float)h10[2 * j + 1] + wv[i].w * (float)h11[2 * j + 1];
                pk[j] = pack_bf16(v0, v1);
            }
            uint4 wv4 = make_uint4(pk[0], pk[1], pk[2], pk[3]);
            __builtin_memcpy(tb + lan * 1024 + ((p << 4) ^ (lan << 4)), &wv4, 16);
        }
    };

    // prologue: build tile[0] for tap 0
    issue_half(0, 0, gA, wvA);
    pack_half(0, 0, gA, wvA);
    issue_half(0, 2, gB, wvB);
    pack_half(0, 2, gB, wvB);
    __syncthreads();

    for (int kk = 0; kk < 9; ++kk) {
        const int buf = kk & 1, nbuf = (kk + 1) & 1;

        // batch-preload this tap's weight fragments (issued before gathers,
        // so the MFMA halves can wait on ua while gathers stay in flight)
#pragma unroll
        for (int ks = 0; ks < 16; ++ks) {
            int kul = ks * 2 + h;
            ua[ks] = wb4[((size_t)wid * 288 + kk * 32 + kul) * 32 + lan];
        }
        if (kk < 8) issue_half(kk + 1, 0, gA, wvA);

        {   // MFMA ks 0..7
            const char* tb = (const char*)&tile[buf][0];
#pragma unroll
            for (int ks = 0; ks < 8; ++ks) {
                int kul = ks * 2 + h;
                uint4 ub0, ub1;
                __builtin_memcpy(&ub0, tb + kul * 1024 + ((lan << 4) ^ (kul << 4)), 16);
                __builtin_memcpy(&ub1, tb + kul * 1024 + (((32 + lan) << 4) ^ (kul << 4)), 16);
                short8 a, b0, b1;
                __builtin_memcpy(&a, &ua[ks], 16);
                __builtin_memcpy(&b0, &ub0, 16);
                __builtin_memcpy(&b1, &ub1, 16);
                acc0 = __builtin_amdgcn_mfma_f32_32x32x16_bf16(a, b0, acc0, 0, 0, 0);
                acc1 = __builtin_amdgcn_mfma_f32_32x32x16_bf16(a, b1, acc1, 0, 0, 0);
            }
        }

        if (kk < 8) {
            pack_half(nbuf, 0, gA, wvA);
            issue_half(kk + 1, 2, gB, wvB);
        }

        {   // MFMA ks 8..15
            const char* tb = (const char*)&tile[buf][0];
#pragma unroll
            for (int ks = 8; ks < 16; ++ks) {
                int kul = ks * 2 + h;
                uint4 ub0, ub1;
                __builtin_memcpy(&ub0, tb + kul * 1024 + ((lan << 4) ^ (kul << 4)), 16);
                __builtin_memcpy(&ub1, tb + kul * 1024 + (((32 + lan) << 4) ^ (kul << 4)), 16);
                short8 a, b0, b1;
                __builtin_memcpy(&a, &ua[ks], 16);
                __builtin_memcpy(&b0, &ub0, 16);
                __builtin_memcpy(&b1, &ub1, 16);
                acc0 = __builtin_amdgcn_mfma_f32_32x32x16_bf16(a, b0, acc0, 0, 0, 0);
                acc1 = __builtin_amdgcn_mfma_f32_32x32x16_bf16(a, b1, acc1, 0, 0, 0);
            }
        }

        if (kk < 8) pack_half(nbuf, 2, gB, wvB);
        __syncthreads();
    }

    // epilogue: wave wid owns m-tile wid, 2 n-tiles (verbatim)
#pragma unroll
    for (int nt = 0; nt < 2; ++nt) {
#pragma unroll
        for (int r = 0; r < 16; ++r) {
            int o = wid * 32 + (r & 3) + 8 * (r >> 2) + 4 * h;
            int woo = nt * 32 + lan;
            float v = (nt == 0) ? acc0[r] : acc1[r];
            out[(((size_t)b * 256 + o) * 64 + ho) * 64 + woo] = v + biasl[o];
        }
    }
}

extern "C" void kernel_launch(void* const* d_in, const int* in_sizes, int n_in,
                              void* d_out, int out_size, void* d_ws, size_t ws_size,
                              hipStream_t stream) {
    const float* x      = (const float*)d_in[0];
    const float* weight = (const float*)d_in[1];
    const float* bias   = (const float*)d_in[2];
    const float* off_w  = (const float*)d_in[3];
    const float* off_b  = (const float*)d_in[4];
    const float* mask_w = (const float*)d_in[5];
    const float* mask_b = (const float*)d_in[6];
    float* out = (float*)d_out;

    float* ws_off = (float*)d_ws;                                      // 1,769,472 B
    unsigned short* ws_b  = (unsigned short*)((char*)d_ws + 1769472);  // 1,179,648 B
    unsigned short* ws_a2 = (unsigned short*)((char*)d_ws + 2949120);  //   147,456 B
    unsigned short* xt    = (unsigned short*)((char*)d_ws + 3096576);  // 8,388,608 B

    hipLaunchKernelGGL(weight_pack_kernel, dim3(100), dim3(256), 0, stream,
                       weight, off_w, mask_w, ws_b, ws_a2);
    hipLaunchKernelGGL(xpose_hwc_kernel, dim3(256), dim3(256), 0, stream,
                       x, xt);
    hipLaunchKernelGGL(offmask_mfma_kernel, dim3(256), dim3(512), 0, stream,
                       xt, ws_a2, off_b, mask_b, ws_off);
    hipLaunchKernelGGL(deform_gemm_kernel, dim3(256), dim3(512), 0, stream,
                       xt, ws_off, ws_b, bias, out);
}